// Round 17
// baseline (90.460 us; speedup 1.0000x reference)
//
#include <hip/hip_runtime.h>

#define B_ 32
#define L_ 1024
#define D_ 128
#define NT 256

typedef __attribute__((ext_vector_type(8))) short bf8_t;
typedef __attribute__((ext_vector_type(4))) short bf4_t;
typedef __attribute__((ext_vector_type(4))) float f4_t;

__device__ __forceinline__ unsigned cvtpk(float lo, float hi) {
  unsigned r;
  asm("v_cvt_pk_bf16_f32 %0, %1, %2" : "=v"(r) : "v"(lo), "v"(hi));
  return r;
}

__device__ __forceinline__ void gload16(const void* g, void* l) {
  __builtin_amdgcn_global_load_lds((const __attribute__((address_space(1))) void*)g,
                                   (__attribute__((address_space(3))) void*)l, 16, 0, 0);
}

// Prologue (R10/R13-verified, unchanged): pre-swizzled bf16 X panels + sq +
// channel-0 copy + W in fragment-coalesced layout Wc[which][j/32][d][j%32].
__global__ __launch_bounds__(256)
void prep_kernel(const float* __restrict__ x0, const float* __restrict__ x1,
                 const float* __restrict__ W0, const float* __restrict__ W1,
                 short* __restrict__ Xs, float* __restrict__ sq,
                 short* __restrict__ Wt, float* __restrict__ out) {
  int bid = blockIdx.x;
  if (bid < 8192) {
    int t = bid * 256 + threadIdx.x;     // 0 .. 2097151
    int row_id = t >> 5;                 // (which,b,row)
    int qp = t & 31;
    int which = row_id >> 15;
    int b = (row_id >> 10) & 31;
    int row = row_id & 1023;
    const float* x = which ? x1 : x0;
    float4 v = *(const float4*)(x + ((size_t)b * L_ + row) * D_ + qp * 4);
    float* o = out + (size_t)which * (B_ * 2 * L_ * D_) + (size_t)b * (2 * L_ * D_)
             + (size_t)row * D_ + qp * 4;
    *(float4*)o = v;
    unsigned w0 = cvtpk(v.x, v.y), w1 = cvtpk(v.z, v.w);
    char* xb = (char*)Xs + (size_t)row_id * 256 + ((qp * 8) ^ ((row & 7) << 4));
    *(uint2*)xb = make_uint2(w0, w1);
    float s = v.x * v.x + v.y * v.y + v.z * v.z + v.w * v.w;
    s += __shfl_xor(s, 1); s += __shfl_xor(s, 2); s += __shfl_xor(s, 4);
    s += __shfl_xor(s, 8); s += __shfl_xor(s, 16);
    if (qp == 0) sq[row_id] = s;
  } else {
    int idx = (bid - 8192) * 256 + threadIdx.x;  // 0..262143
    int which = idx >> 17;
    int rm = idx & 131071;
    int j32 = rm >> 12;       // 32 tiles of 32 j
    int d = (rm >> 5) & 127;
    int jj = rm & 31;
    const float* W = which ? W1 : W0;
    float wv = W[(j32 * 32 + jj) * D_ + d];
    Wt[idx] = (short)(cvtpk(wv, wv) & 0xffffu);
  }
}

__global__ __launch_bounds__(NT, 4)
void fused_attnconv(const short* __restrict__ Xs, const float* __restrict__ sq,
                    const short* __restrict__ Wt, float* __restrict__ out) {
  // LDS: [0,8K) y0 [8K,16K) y1 [16K,24K) P (64 rows x 128B) [24K,28K) sqy
  __shared__ char smem[28672];
  char* Pb = smem + 16384;
  float* sqyL = (float*)(smem + 24576);

  const int bid = blockIdx.x;
  const int x = bid & 7, g = bid >> 3;
  const int p = x + 8 * (g >> 4);       // panel id = which*32+b
  const int it = g & 15;                // i-tile (64 rows)
  const int which = p >> 5, b = p & 31;
  const int i0 = it * 64;
  const int po = (which ^ 1) * 32 + b;  // opposite tensor: y-side

  const char* apanel = (const char*)Xs + (size_t)p * (L_ * 256);
  const char* ypanel = (const char*)Xs + (size_t)po * (L_ * 256);
  const float* sqx_p = sq + p * L_;
  const float* sqy_p = sq + po * L_;
  float* Oc1 = out + (size_t)which * (B_ * 2 * L_ * D_) + (size_t)b * (2 * L_ * D_) + (L_ * D_);

  const int tid = threadIdx.x;
  const int lane = tid & 63;
  const int w = tid >> 6;         // 4 waves: wave = 16 i-rows x 32 j x 128 d
  const int l15 = lane & 15;
  const int q = lane >> 4;
  const int I0 = w * 16;
  const int swz = (l15 & 7) << 4;

  // hoisted y-fragment offsets (R13 formulas, JS=0); ST1 rows at +4096B
  const int yo0 = l15 * 256 + ((0 * 64 + q * 16) ^ swz);
  const int yo1 = l15 * 256 + ((1 * 64 + q * 16) ^ swz);
  const int yo2 = l15 * 256 + ((2 * 64 + q * 16) ^ swz);
  const int yo3 = l15 * 256 + ((3 * 64 + q * 16) ^ swz);
  // P write/read offsets (R13 formulas; JS=0 and JS=16 halves, same wave)
  const int pw0 = (I0 + l15) * 128 + ((q * 8) ^ swz);         // j 0..15 half
  const int pw1 = (I0 + l15) * 128 + ((32 + q * 8) ^ swz);    // j 16..31 half
  const int pro = (I0 + l15) * 128 + ((q * 16) ^ swz);        // A-frag read

  // a-fragments in registers (pre-swizzled global layout, R13-verified)
  bf8_t afr[4];
#pragma unroll
  for (int kb = 0; kb < 4; ++kb)
    afr[kb] = *(const bf8_t*)(apanel + (size_t)(i0 + I0 + l15) * 256 + ((kb * 64 + q * 16) ^ swz));
  const float sxv = sqx_p[i0 + I0 + l15];

  // running pointers
  const short* wptr = Wt + which * 131072 + l15 * 32 + q * 8;  // += 4096/iter
  const char* ypref = ypanel + 8192 + (size_t)tid * 16;        // src of tile jt+1
  const float* syp = sqyL + q * 4;                             // += 32/iter

  // stage sqy (4 KB) + y-tile 0 (8 KB: 2 gload16/thread)
  *(f4_t*)(sqyL + tid * 4) = *(const f4_t*)(sqy_p + tid * 4);
  gload16(ypanel + (size_t)tid * 16, smem + tid * 16);
  gload16(ypanel + 4096 + (size_t)tid * 16, smem + 4096 + tid * 16);

  f4_t z4 = {0.f, 0.f, 0.f, 0.f};
  f4_t acc[8];
#pragma unroll
  for (int m = 0; m < 8; ++m) acc[m] = z4;

  __syncthreads();  // vmcnt+lgkm drained: tile 0 + sqy staged

#pragma unroll 1
  for (int jt = 0; jt < 32; ++jt) {
    char* yB = smem + (jt & 1) * 8192;

    // 1) W fragments -> regs (8 x contiguous 1KB, coalesced, L2-hot)
    bf8_t wf[8];
#pragma unroll
    for (int m = 0; m < 8; ++m)
      wf[m] = *(const bf8_t*)(wptr + m * 512);
    wptr += 4096;

    // 2) prefetch next y-tile into the other buffer (read finished at jt-1;
    //    all waves passed the jt-1 end barrier)
    if (jt < 31) {
      char* yN = smem + ((jt + 1) & 1) * 8192;
      gload16(ypref, yN + tid * 16);
      gload16(ypref + 4096, yN + 4096 + tid * 16);
    }
    ypref += 8192;

    // 3) sy for both j-halves
    f4_t sy0 = *(const f4_t*)(syp);
    f4_t sy1 = *(const f4_t*)(syp + 16);
    syp += 32;

    // 4) MFMA-1 (swapped, R13 formulas): ST0 j 0-15 (rows l15), ST1 j 16-31
    f4_t ST0 = z4, ST1 = z4;
    {
      bf8_t ya = *(const bf8_t*)(yB + yo0);
      bf8_t yb = *(const bf8_t*)(yB + 4096 + yo0);
      ST0 = __builtin_amdgcn_mfma_f32_16x16x32_bf16(ya, afr[0], ST0, 0, 0, 0);
      ST1 = __builtin_amdgcn_mfma_f32_16x16x32_bf16(yb, afr[0], ST1, 0, 0, 0);
      ya = *(const bf8_t*)(yB + yo1);
      yb = *(const bf8_t*)(yB + 4096 + yo1);
      ST0 = __builtin_amdgcn_mfma_f32_16x16x32_bf16(ya, afr[1], ST0, 0, 0, 0);
      ST1 = __builtin_amdgcn_mfma_f32_16x16x32_bf16(yb, afr[1], ST1, 0, 0, 0);
      ya = *(const bf8_t*)(yB + yo2);
      yb = *(const bf8_t*)(yB + 4096 + yo2);
      ST0 = __builtin_amdgcn_mfma_f32_16x16x32_bf16(ya, afr[2], ST0, 0, 0, 0);
      ST1 = __builtin_amdgcn_mfma_f32_16x16x32_bf16(yb, afr[2], ST1, 0, 0, 0);
      ya = *(const bf8_t*)(yB + yo3);
      yb = *(const bf8_t*)(yB + 4096 + yo3);
      ST0 = __builtin_amdgcn_mfma_f32_16x16x32_bf16(ya, afr[3], ST0, 0, 0, 0);
      ST1 = __builtin_amdgcn_mfma_f32_16x16x32_bf16(yb, afr[3], ST1, 0, 0, 0);
    }

    // 5) elementwise A = 1/(1+dist) -> wave-private P rows (both j-halves)
    {
      float A0 = __builtin_amdgcn_rcpf(1.0f + __builtin_amdgcn_sqrtf(fmaxf(__builtin_fmaf(-2.f, ST0[0], sxv + sy0[0]), 0.f)));
      float A1 = __builtin_amdgcn_rcpf(1.0f + __builtin_amdgcn_sqrtf(fmaxf(__builtin_fmaf(-2.f, ST0[1], sxv + sy0[1]), 0.f)));
      float A2 = __builtin_amdgcn_rcpf(1.0f + __builtin_amdgcn_sqrtf(fmaxf(__builtin_fmaf(-2.f, ST0[2], sxv + sy0[2]), 0.f)));
      float A3 = __builtin_amdgcn_rcpf(1.0f + __builtin_amdgcn_sqrtf(fmaxf(__builtin_fmaf(-2.f, ST0[3], sxv + sy0[3]), 0.f)));
      union { uint2 u; bf4_t s; } p0;
      p0.u = make_uint2(cvtpk(A0, A1), cvtpk(A2, A3));
      *(bf4_t*)(Pb + pw0) = p0.s;   // short-typed store: same TBAA family as read
      float B0 = __builtin_amdgcn_rcpf(1.0f + __builtin_amdgcn_sqrtf(fmaxf(__builtin_fmaf(-2.f, ST1[0], sxv + sy1[0]), 0.f)));
      float B1 = __builtin_amdgcn_rcpf(1.0f + __builtin_amdgcn_sqrtf(fmaxf(__builtin_fmaf(-2.f, ST1[1], sxv + sy1[1]), 0.f)));
      float B2 = __builtin_amdgcn_rcpf(1.0f + __builtin_amdgcn_sqrtf(fmaxf(__builtin_fmaf(-2.f, ST1[2], sxv + sy1[2]), 0.f)));
      float B3 = __builtin_amdgcn_rcpf(1.0f + __builtin_amdgcn_sqrtf(fmaxf(__builtin_fmaf(-2.f, ST1[3], sxv + sy1[3]), 0.f)));
      union { uint2 u; bf4_t s; } p1;
      p1.u = make_uint2(cvtpk(B0, B1), cvtpk(B2, B3));
      *(bf4_t*)(Pb + pw1) = p1.s;
    }

    // Compiler fence: forbid hoisting the P read above the P writes (the
    // no-barrier failures R8/R14/R16 are consistent with exactly that TBAA
    // reorder). HW DS pipe is in-order within a wave, so this costs nothing.
    asm volatile("" ::: "memory");
    __builtin_amdgcn_sched_barrier(0);

    // 6) MFMA-2: wave-private P read; full K=32, all 128 d
    {
      bf8_t pf = *(const bf8_t*)(Pb + pro);
#pragma unroll
      for (int m = 0; m < 8; ++m)
        acc[m] = __builtin_amdgcn_mfma_f32_16x16x32_bf16(pf, wf[m], acc[m], 0, 0, 0);
    }

    __syncthreads();  // single barrier: next y staged + all waves done with yB
  }

  // epilogue: direct store (R10-verified acc mapping; wave owns 16i x 128d)
#pragma unroll
  for (int m = 0; m < 8; ++m) {
    const int d = m * 16 + l15;
#pragma unroll
    for (int r = 0; r < 4; ++r)
      Oc1[(size_t)(i0 + I0 + q * 4 + r) * D_ + d] = acc[m][r];
  }
}

extern "C" void kernel_launch(void* const* d_in, const int* in_sizes, int n_in,
                              void* d_out, int out_size, void* d_ws, size_t ws_size,
                              hipStream_t stream) {
  const float* x0 = (const float*)d_in[0];
  const float* x1 = (const float*)d_in[1];
  const float* W0 = (const float*)d_in[2];
  const float* W1 = (const float*)d_in[3];
  float* out = (float*)d_out;

  char* ws = (char*)d_ws;
  short* Wt = (short*)ws;                       // 512 KB, fragment-coalesced layout
  short* Xs = (short*)(ws + 524288);            // 16.78 MB, pre-swizzled bf16
  float* sq = (float*)(ws + 524288 + 16777216); // 256 KB

  prep_kernel<<<9216, 256, 0, stream>>>(x0, x1, W0, W1, Xs, sq, Wt, out);
  fused_attnconv<<<1024, NT, 0, stream>>>(Xs, sq, Wt, out);
}